// Round 6
// baseline (347.530 us; speedup 1.0000x reference)
//
#include <hip/hip_runtime.h>
#include <math.h>

#define BB 256
#define II 2048
#define CC 10
#define DOUT 16
#define COW 160          // C*DOUT
#define BT 64            // b per block (routing kernel) -> c wave-uniform
#define NTHR 640         // BT * CC
#define RC 2             // i's per routing step
#define A_ST (RC*CC+1)   // 21, odd -> conflict-free

typedef short  short8v __attribute__((ext_vector_type(8)));
typedef float  f32x4   __attribute__((ext_vector_type(4)));

__device__ __forceinline__ ushort f2bf(float x) {   // RNE f32 -> bf16 bits
    union { float f; unsigned u; } v; v.f = x;
    unsigned r = v.u + 0x7fff + ((v.u >> 16) & 1);
    return (ushort)(r >> 16);
}

__device__ __forceinline__ float dot8(const float4& a0, const float4& a1,
                                      const float4& b0, const float4& b1) {
    return a0.x*b0.x + a0.y*b0.y + a0.z*b0.z + a0.w*b0.w
         + a1.x*b1.x + a1.y*b1.y + a1.z*b1.z + a1.w*b1.w;
}

// ---------------- MODE 0 via MFMA ----------------
// s_partial[b,c,o] = 0.1 * sum_{i in tile, d} W[i,c,o,d] * u[b,i,d]
// Per c: GEMM  M=16 b (4 wave-quadrants), N=16 o, K=4i x 8d = 32.
// A: u-tile bf16 in LDS (XOR-swizzled 16B cols). B: W from global f32->bf16.
template<int LEN>
__global__ __launch_bounds__(256, 4)
void caps_pass0_mfma(const float* __restrict__ u, const float* __restrict__ W,
                     float* __restrict__ p)
{
    __shared__ ushort u_lds[64 * LEN * 8];   // [b][i^swz][d] bf16

    const int tid  = threadIdx.x;
    const int l    = tid & 63;
    const int quad = tid >> 6;               // 4 waves = 4 b-quadrants
    const int bbase = blockIdx.y * 64;
    const int i0    = blockIdx.x * LEN;

    // ---- stage u f32 -> bf16, coalesced reads, swizzled LDS ----
    const int ROWF = LEN * 8;                // floats per b-row
    for (int e = tid * 4; e < 64 * ROWF; e += 256 * 4) {
        const int rb = e / ROWF, er = e % ROWF;
        const int i = er >> 3, dh = er & 7;  // dh in {0,4}
        const float4 x = *(const float4*)(u + ((size_t)(bbase + rb) * II + i0 + i) * 8 + dh);
        ushort4 h;
        h.x = f2bf(x.x); h.y = f2bf(x.y); h.z = f2bf(x.z); h.w = f2bf(x.w);
        const int col = i ^ (rb & 7);
        *(ushort4*)&u_lds[rb * ROWF + col * 8 + dh] = h;
    }
    __syncthreads();

    f32x4 acc[CC];
#pragma unroll
    for (int c = 0; c < CC; ++c) acc[c] = (f32x4){0.f, 0.f, 0.f, 0.f};

    const int arow = quad * 16 + (l & 15);   // A row = b within tile
#pragma unroll
    for (int g = 0; g < LEN / 4; ++g) {
        const int ia = g * 4 + (l >> 4);     // this lane's i (k-group)
        const short8v af =
            *(const short8v*)&u_lds[arow * ROWF + ((ia ^ (arow & 7)) * 8)];
        const float4* wg = (const float4*)(W + (size_t)(i0 + ia) * CC * 128 + (l & 15) * 8);
#pragma unroll
        for (int c = 0; c < CC; ++c) {
            const float4 w0 = wg[c * 32 + 0];
            const float4 w1 = wg[c * 32 + 1];
            short8v bf;
            bf[0] = (short)f2bf(w0.x); bf[1] = (short)f2bf(w0.y);
            bf[2] = (short)f2bf(w0.z); bf[3] = (short)f2bf(w0.w);
            bf[4] = (short)f2bf(w1.x); bf[5] = (short)f2bf(w1.y);
            bf[6] = (short)f2bf(w1.z); bf[7] = (short)f2bf(w1.w);
            acc[c] = __builtin_amdgcn_mfma_f32_16x16x32_bf16(af, bf, acc[c], 0, 0, 0);
        }
    }

    // ---- write partials: C/D col = lane&15 (o), row = (lane>>4)*4+r (b) ----
    float* pp = p + (size_t)blockIdx.x * (BB * COW);
#pragma unroll
    for (int c = 0; c < CC; ++c)
#pragma unroll
        for (int r = 0; r < 4; ++r) {
            const int b = bbase + quad * 16 + (l >> 4) * 4 + r;
            pp[b * COW + c * DOUT + (l & 15)] = acc[c][r] * 0.1f;
        }
}

// ---------------- MODES 1/2 (f32 routing, round-5 structure) ----------------
// MODE 1: a = uh.v0. MODE 2: a = uh.(v0+v1). W via wave-uniform scalar loads.
template<int MODE, int LEN>
__global__ __launch_bounds__(NTHR, 8)
void caps_pass(const float* __restrict__ u, const float* __restrict__ W,
               const float* __restrict__ v0, const float* __restrict__ v1,
               float* __restrict__ p)
{
    __shared__ float4 u_lds[16][65];         // [r=il*2+q][bl], SC=8 i's
    __shared__ float  a_lds[2][BT * A_ST];   // ping-pong

    const int tid = threadIdx.x;
    const int bl  = tid & 63;
    const int c   = __builtin_amdgcn_readfirstlane(tid >> 6);
    const int bbase = blockIdx.y * BT;
    const int b   = bbase + bl;
    const int i0  = blockIdx.x * LEN;
    constexpr int SC  = 8;
    constexpr int NCH = LEN / SC;

    float vreg[DOUT];
    {
        const float4* vp0 = (const float4*)(v0 + b * COW + c * DOUT);
        const float4* vp1 = (const float4*)(v1 + b * COW + c * DOUT);
#pragma unroll
        for (int q = 0; q < 4; ++q) {
            float4 x = vp0[q];
            if constexpr (MODE == 2) {
                float4 y = vp1[q];
                x.x += y.x; x.y += y.y; x.z += y.z; x.w += y.w;
            }
            vreg[4*q+0] = x.x; vreg[4*q+1] = x.y; vreg[4*q+2] = x.z; vreg[4*q+3] = x.w;
        }
    }

    float acc[DOUT];
#pragma unroll
    for (int o = 0; o < DOUT; ++o) acc[o] = 0.f;

    const float4* u4 = (const float4*)u;
    const float4* W4 = (const float4*)W;

#pragma unroll
    for (int chk = 0; chk < NCH; ++chk) {
        const int ib = i0 + chk * SC;

        for (int idx = tid; idx < BT * SC * 2; idx += NTHR) {
            const int r = idx & 15, blb = idx >> 4;
            u_lds[r][blb] = u4[((size_t)(bbase + blb) * II + ib + (r >> 1)) * 2 + (r & 1)];
        }
        __syncthreads();

#pragma unroll
        for (int rc = 0; rc < SC / RC; ++rc) {
            const int par = rc & 1;
            float uh[RC][DOUT];

#pragma unroll
            for (int ic = 0; ic < RC; ++ic) {
                const int il = rc * RC + ic;
                const float4 ua = u_lds[il*2 + 0][bl];
                const float4 ub = u_lds[il*2 + 1][bl];
                const float4* wp = W4 + ((size_t)(ib + il) * CC + c) * 32;  // uniform
                float ap = 0.f;
#pragma unroll
                for (int o = 0; o < DOUT; ++o) {
                    float4 w0 = wp[2*o + 0];
                    float4 w1 = wp[2*o + 1];
                    uh[ic][o] = dot8(w0, w1, ua, ub);
                    ap += uh[ic][o] * vreg[o];
                }
                a_lds[par][bl * A_ST + ic * CC + c] = ap;
            }

            __syncthreads();
#pragma unroll
            for (int ic = 0; ic < RC; ++ic) {
                const float* row = &a_lds[par][bl * A_ST + ic * CC];
                float e[CC];
                float m = row[0];
#pragma unroll
                for (int k = 1; k < CC; ++k) m = fmaxf(m, row[k]);
                float sum = 0.f;
#pragma unroll
                for (int k = 0; k < CC; ++k) { e[k] = __expf(row[k] - m); sum += e[k]; }
                const float cw = e[c] / sum;
#pragma unroll
                for (int o = 0; o < DOUT; ++o) acc[o] += cw * uh[ic][o];
            }
        }
        if constexpr (NCH > 1) __syncthreads();
    }

    float4* pp = (float4*)(p + (size_t)blockIdx.x * (BB * COW) + b * COW + c * DOUT);
#pragma unroll
    for (int q = 0; q < 4; ++q)
        pp[q] = make_float4(acc[4*q+0], acc[4*q+1], acc[4*q+2], acc[4*q+3]);
}

// one wave per (b,c): sum partials over nsplit, squash, write vout
__global__ __launch_bounds__(64)
void reduce_squash(const float* __restrict__ p, int nsplit, float* __restrict__ vout)
{
    const int bc = blockIdx.x;
    const int b = bc / CC, c = bc % CC;
    const int l = threadIdx.x;
    const int o = l & 15, g = l >> 4;
    const float* base = p + (size_t)b * COW + c * DOUT + o;

    float s = 0.f;
    for (int sp = g; sp < nsplit; sp += 4)
        s += base[(size_t)sp * (BB * COW)];
    s += __shfl_xor(s, 16);
    s += __shfl_xor(s, 32);
    float sq = s * s;
    sq += __shfl_xor(sq, 1);
    sq += __shfl_xor(sq, 2);
    sq += __shfl_xor(sq, 4);
    sq += __shfl_xor(sq, 8);
    const float scale = (sq / (1.f + sq)) * rsqrtf(sq + 1e-9f);
    if (l < 16) vout[b * COW + c * DOUT + o] = s * scale;
}

template<int LEN>
static void launch_all(const float* u, const float* W, float* out,
                       float* v0, float* v1, float* p, int nsplit,
                       hipStream_t stream)
{
    dim3 grid(nsplit, BB / BT);
    caps_pass0_mfma<LEN><<<dim3(nsplit, 4), 256, 0, stream>>>(u, W, p);
    reduce_squash<<<BB * CC, 64, 0, stream>>>(p, nsplit, v0);
    caps_pass<1, LEN><<<grid, NTHR, 0, stream>>>(u, W, v0, v0, p);
    reduce_squash<<<BB * CC, 64, 0, stream>>>(p, nsplit, v1);
    caps_pass<2, LEN><<<grid, NTHR, 0, stream>>>(u, W, v0, v1, p);
    reduce_squash<<<BB * CC, 64, 0, stream>>>(p, nsplit, out);
}

extern "C" void kernel_launch(void* const* d_in, const int* in_sizes, int n_in,
                              void* d_out, int out_size, void* d_ws, size_t ws_size,
                              hipStream_t stream)
{
    const float* u = (const float*)d_in[0];   // [256,2048,8]
    const float* W = (const float*)d_in[1];   // [2048,10,16,8]
    float* out = (float*)d_out;               // [256,10,16]

    const size_t SEG = (size_t)BB * COW;
    float* v0 = (float*)d_ws;
    float* v1 = v0 + SEG;
    float* p  = v1 + SEG;

    const size_t avail_f = ws_size / sizeof(float);
    int nsplit = 256;                          // prefer LEN=8 (occupancy)
    while (nsplit > 32 && (2 * SEG + (size_t)nsplit * SEG) > avail_f) nsplit >>= 1;

    switch (nsplit) {
        case 256: launch_all<8>(u, W, out, v0, v1, p, 256, stream); break;
        case 128: launch_all<16>(u, W, out, v0, v1, p, 128, stream); break;
        case 64:  launch_all<32>(u, W, out, v0, v1, p, 64, stream); break;
        default:  launch_all<64>(u, W, out, v0, v1, p, 32, stream); break;
    }
}

// Round 7
// 174.393 us; speedup vs baseline: 1.9928x; 1.9928x over previous
//
#include <hip/hip_runtime.h>
#include <math.h>

#define BB 256
#define II 2048
#define CC 10
#define DOUT 16
#define COW 160          // C*DOUT

typedef short  short8v __attribute__((ext_vector_type(8)));
typedef float  f32x4   __attribute__((ext_vector_type(4)));

__device__ __forceinline__ ushort f2bf(float x) {   // RNE f32 -> bf16 bits
    union { float f; unsigned u; } v; v.f = x;
    unsigned r = v.u + 0x7fff + ((v.u >> 16) & 1);
    return (ushort)(r >> 16);
}
__device__ __forceinline__ float bf2f(ushort h) {
    union { unsigned u; float f; } v; v.u = ((unsigned)h) << 16; return v.f;
}
__device__ __forceinline__ short8v pack8(float a0, float a1, float a2, float a3,
                                         float b0, float b1, float b2, float b3) {
    short8v r;
    r[0]=(short)f2bf(a0); r[1]=(short)f2bf(a1); r[2]=(short)f2bf(a2); r[3]=(short)f2bf(a3);
    r[4]=(short)f2bf(b0); r[5]=(short)f2bf(b1); r[6]=(short)f2bf(b2); r[7]=(short)f2bf(b3);
    return r;
}

// ---------------- MODE 0 via MFMA (validated round 6) ----------------
template<int LEN>
__global__ __launch_bounds__(256, 4)
void caps_pass0_mfma(const float* __restrict__ u, const float* __restrict__ W,
                     float* __restrict__ p)
{
    __shared__ ushort u_lds[64 * LEN * 8];   // [b][i^swz][d] bf16

    const int tid  = threadIdx.x;
    const int l    = tid & 63;
    const int quad = tid >> 6;
    const int bbase = blockIdx.y * 64;
    const int i0    = blockIdx.x * LEN;

    const int ROWF = LEN * 8;
    for (int e = tid * 4; e < 64 * ROWF; e += 1024) {
        const int rb = e / ROWF, er = e % ROWF;
        const int i = er >> 3, dh = er & 7;
        const float4 x = *(const float4*)(u + ((size_t)(bbase + rb) * II + i0 + i) * 8 + dh);
        ushort4 h;
        h.x = f2bf(x.x); h.y = f2bf(x.y); h.z = f2bf(x.z); h.w = f2bf(x.w);
        *(ushort4*)&u_lds[rb * ROWF + (i ^ (rb & 7)) * 8 + dh] = h;
    }
    __syncthreads();

    f32x4 acc[CC];
#pragma unroll
    for (int c = 0; c < CC; ++c) acc[c] = (f32x4){0.f, 0.f, 0.f, 0.f};

    const int arow = quad * 16 + (l & 15);
#pragma unroll
    for (int g = 0; g < LEN / 4; ++g) {
        const int ia = g * 4 + (l >> 4);
        const short8v af = *(const short8v*)&u_lds[arow * ROWF + ((ia ^ (arow & 7)) * 8)];
        const float4* wg = (const float4*)(W + (size_t)(i0 + ia) * CC * 128 + (l & 15) * 8);
#pragma unroll
        for (int c = 0; c < CC; ++c) {
            const float4 w0 = wg[c * 32 + 0];
            const float4 w1 = wg[c * 32 + 1];
            const short8v bf = pack8(w0.x, w0.y, w0.z, w0.w, w1.x, w1.y, w1.z, w1.w);
            acc[c] = __builtin_amdgcn_mfma_f32_16x16x32_bf16(af, bf, acc[c], 0, 0, 0);
        }
    }

    float* pp = p + (size_t)blockIdx.x * (BB * COW);
#pragma unroll
    for (int c = 0; c < CC; ++c)
#pragma unroll
        for (int r = 0; r < 4; ++r) {
            const int b = bbase + quad * 16 + (l >> 4) * 4 + r;
            pp[b * COW + c * DOUT + (l & 15)] = acc[c][r] * 0.1f;
        }
}

// ---------------- MODES 1/2 via MFMA (transposed u_hat^T[o,b]) ----------------
// Per wave (= b-quadrant of 16), per i-quad (4 i's, K=32=(i,d)):
//   A = W[i_g, c, o=l&15, d=e]       (rows = o, shared across waves)
//   u_hat MFMA j: B_j = (g==j)? u8 : 0  -> uh_T[o, b] per i
//   agreement: in-lane dot4 over o-rows + shfl_xor(16,32) -> a_lds
//   softmax over c per (b,i) row (no max-sub: |logit| small, f32-safe)
//   fold MFMA: B = cij[b,i_g,c] * u8  (full K=32, sums the i-quad) -> acc_c
template<int MODE, int LEN>
__global__ __launch_bounds__(256, 3)
void caps_route(const float* __restrict__ u, const float* __restrict__ W,
                const float* __restrict__ v0, const float* __restrict__ v1,
                float* __restrict__ p)
{
    constexpr int RF = LEN * 8;              // bf16 elems per b-row
    __shared__ ushort u_lds[64 * RF];
    __shared__ float  a_lds[2][256 * 11];    // [(b_loc*4+ii)*11 + c]

    const int tid = threadIdx.x;
    const int l   = tid & 63;
    const int wq  = tid >> 6;                // wave's b-quadrant
    const int o4  = l & 15;                  // B/D col (b-rel), A row (o)
    const int g   = l >> 4;                  // k-group
    const int bbase = blockIdx.y * 64;
    const int i0    = blockIdx.x * LEN;

    // ---- stage u -> bf16 LDS (pass0-validated layout/swizzle) ----
    for (int e = tid * 4; e < 64 * RF; e += 1024) {
        const int rb = e / RF, er = e % RF;
        const int i = er >> 3, dh = er & 7;
        const float4 x = *(const float4*)(u + ((size_t)(bbase + rb) * II + i0 + i) * 8 + dh);
        ushort4 h;
        h.x = f2bf(x.x); h.y = f2bf(x.y); h.z = f2bf(x.z); h.w = f2bf(x.w);
        *(ushort4*)&u_lds[rb * RF + (i ^ (rb & 7)) * 8 + dh] = h;
    }

    // ---- v regs: vreg[c][r] = v[b_lane, c, o=4g+r] ----
    const int brow  = wq * 16 + o4;          // block-local b of this lane
    const int b_abs = bbase + brow;
    float vreg[CC][4];
#pragma unroll
    for (int c = 0; c < CC; ++c)
#pragma unroll
        for (int r = 0; r < 4; ++r) {
            const int idx = b_abs * COW + c * DOUT + 4 * g + r;
            float x = v0[idx];
            if constexpr (MODE == 2) x += v1[idx];
            vreg[c][r] = x;
        }

    f32x4 acc[CC];
#pragma unroll
    for (int c = 0; c < CC; ++c) acc[c] = (f32x4){0.f, 0.f, 0.f, 0.f};
    const short8v zero8 = {0,0,0,0,0,0,0,0};
    const f32x4   zacc  = (f32x4){0.f, 0.f, 0.f, 0.f};

    __syncthreads();

    for (int iq = 0; iq < LEN / 4; ++iq) {
        const int par = iq & 1;
        // B-source: u8 = u[b_lane, i = iq*4+g, 0..7] bf16
        const short8v u8 = *(const short8v*)
            &u_lds[brow * RF + (((iq * 4 + g) ^ (brow & 7)) * 8)];
        float uf[8];
#pragma unroll
        for (int e = 0; e < 8; ++e) uf[e] = bf2f((ushort)u8[e]);

        short8v w8[CC];
        // ---- u_hat MFMAs + agreement ----
#pragma unroll
        for (int c = 0; c < CC; ++c) {
            const float* wp = W + ((size_t)(i0 + iq * 4 + g) * CC + c) * 128 + o4 * 8;
            const float4 w0 = *(const float4*)wp;
            const float4 w1 = *(const float4*)(wp + 4);
            w8[c] = pack8(w0.x, w0.y, w0.z, w0.w, w1.x, w1.y, w1.z, w1.w);
            f32x4 uh[4];
#pragma unroll
            for (int j = 0; j < 4; ++j)
                uh[j] = __builtin_amdgcn_mfma_f32_16x16x32_bf16(
                    w8[c], (g == j) ? u8 : zero8, zacc, 0, 0, 0);
#pragma unroll
            for (int j = 0; j < 4; ++j) {
                float t = uh[j][0] * vreg[c][0] + uh[j][1] * vreg[c][1]
                        + uh[j][2] * vreg[c][2] + uh[j][3] * vreg[c][3];
                t += __shfl_xor(t, 16);
                t += __shfl_xor(t, 32);
                if (l < 16) a_lds[par][((wq * 16 + l) * 4 + j) * 11 + c] = t;
            }
        }
        __syncthreads();

        // ---- softmax over c: row = tid = (b_loc*4 + ii) ----
        {
            float ex[CC];
            float s = 0.f;
#pragma unroll
            for (int c = 0; c < CC; ++c) { ex[c] = __expf(a_lds[par][tid * 11 + c]); s += ex[c]; }
            const float inv = 1.f / s;
#pragma unroll
            for (int c = 0; c < CC; ++c) a_lds[par][tid * 11 + c] = ex[c] * inv;
        }
        __syncthreads();

        // ---- fold: acc_c += W * (cij .* u), full K over the i-quad ----
#pragma unroll
        for (int c = 0; c < CC; ++c) {
            const float cw = a_lds[par][(brow * 4 + g) * 11 + c];
            const short8v bf = pack8(cw * uf[0], cw * uf[1], cw * uf[2], cw * uf[3],
                                     cw * uf[4], cw * uf[5], cw * uf[6], cw * uf[7]);
            acc[c] = __builtin_amdgcn_mfma_f32_16x16x32_bf16(w8[c], bf, acc[c], 0, 0, 0);
        }
        // next iq uses the other a_lds buffer -> no extra barrier
    }

    // ---- write partials: 4 g-lanes of one b cover 64B contiguous ----
    float* pp = p + (size_t)blockIdx.x * (BB * COW) + (size_t)b_abs * COW;
#pragma unroll
    for (int c = 0; c < CC; ++c) {
        float4 st = make_float4(acc[c][0], acc[c][1], acc[c][2], acc[c][3]);
        *(float4*)(pp + c * DOUT + 4 * g) = st;
    }
}

// one wave per (b,c): sum partials over nsplit, squash, write vout
__global__ __launch_bounds__(64)
void reduce_squash(const float* __restrict__ p, int nsplit, float* __restrict__ vout)
{
    const int bc = blockIdx.x;
    const int b = bc / CC, c = bc % CC;
    const int l = threadIdx.x;
    const int o = l & 15, g = l >> 4;
    const float* base = p + (size_t)b * COW + c * DOUT + o;

    float s = 0.f;
    for (int sp = g; sp < nsplit; sp += 4)
        s += base[(size_t)sp * (BB * COW)];
    s += __shfl_xor(s, 16);
    s += __shfl_xor(s, 32);
    float sq = s * s;
    sq += __shfl_xor(sq, 1);
    sq += __shfl_xor(sq, 2);
    sq += __shfl_xor(sq, 4);
    sq += __shfl_xor(sq, 8);
    const float scale = (sq / (1.f + sq)) * rsqrtf(sq + 1e-9f);
    if (l < 16) vout[b * COW + c * DOUT + o] = s * scale;
}

template<int LEN>
static void launch_all(const float* u, const float* W, float* out,
                       float* v0, float* v1, float* p, int nsplit,
                       hipStream_t stream)
{
    dim3 grid(nsplit, BB / 64);
    caps_pass0_mfma<LEN><<<grid, 256, 0, stream>>>(u, W, p);
    reduce_squash<<<BB * CC, 64, 0, stream>>>(p, nsplit, v0);
    caps_route<1, LEN><<<grid, 256, 0, stream>>>(u, W, v0, v0, p);
    reduce_squash<<<BB * CC, 64, 0, stream>>>(p, nsplit, v1);
    caps_route<2, LEN><<<grid, 256, 0, stream>>>(u, W, v0, v1, p);
    reduce_squash<<<BB * CC, 64, 0, stream>>>(p, nsplit, out);
}

extern "C" void kernel_launch(void* const* d_in, const int* in_sizes, int n_in,
                              void* d_out, int out_size, void* d_ws, size_t ws_size,
                              hipStream_t stream)
{
    const float* u = (const float*)d_in[0];   // [256,2048,8]
    const float* W = (const float*)d_in[1];   // [2048,10,16,8]
    float* out = (float*)d_out;               // [256,10,16]

    const size_t SEG = (size_t)BB * COW;
    float* v0 = (float*)d_ws;
    float* v1 = v0 + SEG;
    float* p  = v1 + SEG;

    const size_t avail_f = ws_size / sizeof(float);
    int nsplit = 256;
    while (nsplit > 32 && (2 * SEG + (size_t)nsplit * SEG) > avail_f) nsplit >>= 1;

    switch (nsplit) {
        case 256: launch_all<8>(u, W, out, v0, v1, p, 256, stream); break;
        case 128: launch_all<16>(u, W, out, v0, v1, p, 128, stream); break;
        case 64:  launch_all<32>(u, W, out, v0, v1, p, 64, stream); break;
        default:  launch_all<64>(u, W, out, v0, v1, p, 32, stream); break;
    }
}